// Round 2
// baseline (389.299 us; speedup 1.0000x reference)
//
#include <hip/hip_runtime.h>
#include <math.h>

#define NN   8192
#define EE   262144
#define CIN  64
#define DD   192      // IN_C*K = OUT_C*K
#define GG   64
#define NCLS 10
#define D3   576      // 3*DD
#define F1   384
#define F2   192
#define EPSB 1e-5f

// ---------------- setup kernels ----------------

__global__ void zero_kernel(int* __restrict__ p, int n) {
    int t = blockIdx.x * blockDim.x + threadIdx.x;
    if (t < n) p[t] = 0;
}

__global__ void count_kernel(const int* __restrict__ ei,
                             const int* __restrict__ batch,
                             int* __restrict__ deg, int* __restrict__ gcnt) {
    int t = blockIdx.x * blockDim.x + threadIdx.x;
    if (t < EE) atomicAdd(&deg[ei[t]], 1);          // row = ei[0:E]
    if (t < NN) atomicAdd(&gcnt[batch[t]], 1);
}

// one block, 256 threads: exclusive scan of deg[8192] -> rowptr, dinv, gstart
__global__ void scan_kernel(const int* __restrict__ deg, int* __restrict__ rowptr,
                            float* __restrict__ dinv, const int* __restrict__ gcnt,
                            int* __restrict__ gstart) {
    __shared__ int part[256];
    int t = threadIdx.x;
    int local[32];
    int base = t * 32;
    int s = 0;
    for (int i = 0; i < 32; i++) { local[i] = s; s += deg[base + i]; }
    part[t] = s;
    __syncthreads();
    for (int off = 1; off < 256; off <<= 1) {
        int v = (t >= off) ? part[t - off] : 0;
        __syncthreads();
        part[t] += v;
        __syncthreads();
    }
    int prefix = (t > 0) ? part[t - 1] : 0;
    for (int i = 0; i < 32; i++) rowptr[base + i] = prefix + local[i];
    if (t == 255) rowptr[NN] = part[255];
    for (int i = 0; i < 32; i++) {
        int d = deg[base + i];
        dinv[base + i] = (d > 0) ? rsqrtf((float)d) : 0.f;
    }
    if (t == 0) {
        int s2 = 0;
        for (int g = 0; g < GG; g++) { gstart[g] = s2; s2 += gcnt[g]; }
    }
}

__global__ void scatter_kernel(const int* __restrict__ ei,
                               const int* __restrict__ rowptr, int* __restrict__ cursor,
                               int* __restrict__ csr_col) {
    int e = blockIdx.x * blockDim.x + threadIdx.x;
    if (e >= EE) return;
    int r = ei[e];
    int c = ei[EE + e];
    int pos = rowptr[r] + atomicAdd(&cursor[r], 1);
    csr_col[pos] = c;
}

__global__ void copyx_kernel(const float* __restrict__ x, float* __restrict__ Hcat) {
    int idx = blockIdx.x * 256 + threadIdx.x;   // < NN*CIN
    int n = idx >> 6, c = idx & 63;
    Hcat[n * DD + c] = x[idx];
}

// one wave per row; lane = channel.
// out = h_row - dinv[row] * sum_e dinv[col_e] * h[col_e]
__global__ __launch_bounds__(256) void spmm_kernel(const float* __restrict__ hin,
    int in_stride, int in_off,
    const int* __restrict__ rowptr, const int* __restrict__ col,
    const float* __restrict__ dinv,
    float* __restrict__ Hcat, int coff) {
    int idx = blockIdx.x * 256 + threadIdx.x;
    int row = idx >> 6, lane = idx & 63;
    int s = rowptr[row], e = rowptr[row + 1];
    float acc = 0.f;
    for (int p = s; p < e; p++) {
        int c = col[p];                       // broadcast (wave-uniform)
        acc += dinv[c] * hin[c * in_stride + in_off + lane];
    }
    float self = hin[row * in_stride + in_off + lane];
    Hcat[row * DD + coff + lane] = self - dinv[row] * acc;
}

// ---------------- spectral norm + masked weight (transposed) ----------------

__global__ void specnorm_kernel(const float* __restrict__ W, const float* __restrict__ u,
                                float* __restrict__ WmT) {
    __shared__ float v[DD];
    __shared__ float red[256];
    __shared__ float s_norm, s_sigma;
    int t = threadIdx.x;
    float vv = 0.f;
    if (t < DD) {
        float s = 0.f;
        for (int i = 0; i < DD; i++) s += W[i * DD + t] * u[i];
        v[t] = s;
        vv = s * s;
    }
    red[t] = vv;
    __syncthreads();
    for (int off = 128; off > 0; off >>= 1) {
        if (t < off) red[t] += red[t + off];
        __syncthreads();
    }
    if (t == 0) s_norm = sqrtf(red[0]) + 1e-12f;
    __syncthreads();
    float wv = 0.f;
    if (t < DD) {
        float s = 0.f;
        for (int j = 0; j < DD; j++) s += W[t * DD + j] * v[j];
        wv = u[t] * s;
    }
    red[t] = wv;
    __syncthreads();
    for (int off = 128; off > 0; off >>= 1) {
        if (t < off) red[t] += red[t + off];
        __syncthreads();
    }
    if (t == 0) s_sigma = red[0] / s_norm;
    __syncthreads();
    float inv_sigma = 1.f / s_sigma;
    for (int idx = t; idx < DD * DD; idx += 256) {
        int r = idx / DD, c = idx - r * DD;
        float m = (c < CIN * ((r >> 6) + 1)) ? 1.f : 0.f;
        WmT[c * DD + r] = m * W[idx] * inv_sigma;   // transposed for coalesced GEMM reads
    }
}

// ------ H = Hcat @ WmT + b, IN PLACE on Hcat (row n depends only on row n) ---

__global__ __launch_bounds__(192) void gemm_kernel(float* __restrict__ Hcat,
    const float* __restrict__ WmT, const float* __restrict__ bias) {
    __shared__ float hs[32 * DD];
    int t = threadIdx.x;          // t = output channel
    int n0 = blockIdx.x * 32;
    for (int i = t; i < 32 * DD; i += 192) hs[i] = Hcat[n0 * DD + i];
    __syncthreads();
    float acc[32];
    float bv = bias[t];
#pragma unroll
    for (int r = 0; r < 32; r++) acc[r] = bv;
    for (int k = 0; k < DD; k += 4) {
        float w0 = WmT[(k + 0) * DD + t];
        float w1 = WmT[(k + 1) * DD + t];
        float w2 = WmT[(k + 2) * DD + t];
        float w3 = WmT[(k + 3) * DD + t];
#pragma unroll
        for (int r = 0; r < 32; r++) {
            const float4 h4 = *(const float4*)&hs[r * DD + k];
            acc[r] += h4.x * w0 + h4.y * w1 + h4.z * w2 + h4.w * w3;
        }
    }
    for (int r = 0; r < 32; r++) Hcat[(n0 + r) * DD + t] = acc[r];
}

// ---------------- BN1 stats ----------------

__global__ __launch_bounds__(192) void bnstats_kernel(const float* __restrict__ H,
    float* __restrict__ bsum, float* __restrict__ bsumsq) {
    int c = threadIdx.x;
    int n0 = blockIdx.x * 64;
    float s = 0.f, ss = 0.f;
    for (int i = 0; i < 64; i++) {
        float x = H[(n0 + i) * DD + c];
        s += x; ss += x * x;
    }
    atomicAdd(&bsum[c], s);
    atomicAdd(&bsumsq[c], ss);
}

__global__ void bnfin_kernel(const float* __restrict__ bsum, const float* __restrict__ bsumsq,
                             const float* __restrict__ gamma,
                             float* __restrict__ mu, float* __restrict__ scale) {
    int c = threadIdx.x;   // 192 threads
    float m = bsum[c] / (float)NN;
    float var = bsumsq[c] / (float)NN - m * m;
    mu[c] = m;
    scale[c] = gamma[c] * rsqrtf(var + EPSB);
}

// ---------------- BN1-apply + triple pooling (batch sorted -> segments) ------

__global__ __launch_bounds__(192) void pool_kernel(const float* __restrict__ H,
    const int* __restrict__ gstart, const int* __restrict__ gcnt,
    const float* __restrict__ mu, const float* __restrict__ scale,
    const float* __restrict__ beta, float* __restrict__ Hg) {
    int g = blockIdx.x, c = threadIdx.x;
    int s = gstart[g], n = gcnt[g];
    float m = mu[c], sc = scale[c], bb = beta[c];
    float sum = 0.f, mx = -INFINITY;
    for (int i = 0; i < n; i++) {
        float x = H[(s + i) * DD + c];
        x = sc * (x - m) + bb;
        sum += x;
        mx = fmaxf(mx, x);
    }
    float cf = (float)n;
    Hg[g * D3 + c]          = sum / fmaxf(cf, 1.f);
    Hg[g * D3 + DD + c]     = sum;
    Hg[g * D3 + 2 * DD + c] = mx;
}

// ---------------- BN2 (64 samples x 576 ch), in one block -------------------

__global__ __launch_bounds__(D3) void bn2_kernel(const float* __restrict__ Hg,
    const float* __restrict__ gamma, const float* __restrict__ beta,
    float* __restrict__ Hgn) {
    int c = threadIdx.x;
    float s = 0.f, ss = 0.f;
    for (int g = 0; g < GG; g++) { float x = Hg[g * D3 + c]; s += x; ss += x * x; }
    float m = s / (float)GG;
    float var = ss / (float)GG - m * m;
    float sc = gamma[c] * rsqrtf(var + EPSB);
    float bb = beta[c];
    for (int g = 0; g < GG; g++) Hgn[g * D3 + c] = sc * (Hg[g * D3 + c] - m) + bb;
}

// ---------------- funnel head + log_softmax, one block per graph -------------

__global__ __launch_bounds__(F1) void funnel_kernel(const float* __restrict__ Hgn,
    const float* __restrict__ w1, const float* __restrict__ b1,
    const float* __restrict__ w2, const float* __restrict__ b2,
    const float* __restrict__ w3, const float* __restrict__ b3,
    float* __restrict__ out) {
    __shared__ float hg[D3];
    __shared__ float x1[F1];
    __shared__ float x2[F2];
    __shared__ float lg[NCLS];
    __shared__ float s_lse;
    int g = blockIdx.x, t = threadIdx.x;
    for (int i = t; i < D3; i += F1) hg[i] = Hgn[g * D3 + i];
    __syncthreads();
    {
        float a = b1[t];
        for (int k = 0; k < D3; k++) a += hg[k] * w1[t * D3 + k];
        x1[t] = fmaxf(a, 0.f);
    }
    __syncthreads();
    if (t < F2) {
        float a = b2[t];
        for (int k = 0; k < F1; k++) a += x1[k] * w2[t * F1 + k];
        x2[t] = fmaxf(a, 0.f);
    }
    __syncthreads();
    if (t < NCLS) {
        float a = b3[t];
        for (int k = 0; k < F2; k++) a += x2[k] * w3[t * F2 + k];
        lg[t] = a;
    }
    __syncthreads();
    if (t == 0) {
        float m = lg[0];
        for (int i = 1; i < NCLS; i++) m = fmaxf(m, lg[i]);
        float se = 0.f;
        for (int i = 0; i < NCLS; i++) se += expf(lg[i] - m);
        s_lse = m + logf(se);
    }
    __syncthreads();
    if (t < NCLS) out[g * NCLS + t] = lg[t] - s_lse;
}

// ---------------- launcher ----------------

extern "C" void kernel_launch(void* const* d_in, const int* in_sizes, int n_in,
                              void* d_out, int out_size, void* d_ws, size_t ws_size,
                              hipStream_t stream) {
    (void)in_sizes; (void)n_in; (void)out_size; (void)ws_size;
    const float* x     = (const float*)d_in[0];
    const int*   ei    = (const int*)d_in[1];    // int32 on device (harness contract)
    const int*   batch = (const int*)d_in[2];
    const float* W     = (const float*)d_in[3];
    const float* b     = (const float*)d_in[4];
    const float* u     = (const float*)d_in[5];
    const float* g1    = (const float*)d_in[6];
    const float* be1   = (const float*)d_in[7];
    const float* g2    = (const float*)d_in[8];
    const float* be2   = (const float*)d_in[9];
    const float* w1    = (const float*)d_in[10];
    const float* b1    = (const float*)d_in[11];
    const float* w2    = (const float*)d_in[12];
    const float* b2    = (const float*)d_in[13];
    const float* w3    = (const float*)d_in[14];
    const float* b3    = (const float*)d_in[15];
    float* out = (float*)d_out;
    char*  ws  = (char*)d_ws;

    // ---- workspace layout (bytes), total ~7.6 MB ----
    int*   deg     = (int*)(ws + 0);           // 32768   (zeroed)
    int*   cursor  = (int*)(ws + 32768);       // 32768   (zeroed)
    int*   gcnt    = (int*)(ws + 65536);       // 256     (zeroed)
    float* bsum    = (float*)(ws + 65792);     // 768     (zeroed)
    float* bsumsq  = (float*)(ws + 66560);     // 768     (zeroed; zero region = 67328 B)
    int*   rowptr  = (int*)(ws + 67328);       // 33024
    int*   gstart  = (int*)(ws + 100352);      // 256
    float* dinv    = (float*)(ws + 100608);    // 32768
    int*   csr_col = (int*)(ws + 133376);      // 1048576
    float* Hcat    = (float*)(ws + 1181952);   // 6291456 (also GEMM output, in place)
    float* WmT     = (float*)(ws + 7473408);   // 147456
    float* bmu     = (float*)(ws + 7620864);   // 1024
    float* bscale  = (float*)(ws + 7621888);   // 1024
    float* Hg      = (float*)(ws + 7622912);   // 147456
    float* Hgn     = (float*)(ws + 7770368);   // 147456  -> end 7917824

    zero_kernel<<<66, 256, 0, stream>>>((int*)ws, 16832);
    count_kernel<<<EE / 256, 256, 0, stream>>>(ei, batch, deg, gcnt);
    scan_kernel<<<1, 256, 0, stream>>>(deg, rowptr, dinv, gcnt, gstart);
    scatter_kernel<<<EE / 256, 256, 0, stream>>>(ei, rowptr, cursor, csr_col);
    copyx_kernel<<<NN * CIN / 256, 256, 0, stream>>>(x, Hcat);
    // pass 1: read x [N,64], write Hcat col-block 1
    spmm_kernel<<<NN * 64 / 256, 256, 0, stream>>>(x, CIN, 0, rowptr, csr_col, dinv, Hcat, CIN);
    // pass 2: read Hcat col-block 1 (strided), write Hcat col-block 2
    spmm_kernel<<<NN * 64 / 256, 256, 0, stream>>>(Hcat, DD, CIN, rowptr, csr_col, dinv, Hcat, 2 * CIN);
    specnorm_kernel<<<1, 256, 0, stream>>>(W, u, WmT);
    gemm_kernel<<<NN / 32, 192, 0, stream>>>(Hcat, WmT, b);
    bnstats_kernel<<<NN / 64, 192, 0, stream>>>(Hcat, bsum, bsumsq);
    bnfin_kernel<<<1, 192, 0, stream>>>(bsum, bsumsq, g1, bmu, bscale);
    pool_kernel<<<GG, 192, 0, stream>>>(Hcat, gstart, gcnt, bmu, bscale, be1, Hg);
    bn2_kernel<<<1, D3, 0, stream>>>(Hg, g2, be2, Hgn);
    funnel_kernel<<<GG, F1, 0, stream>>>(Hgn, w1, b1, w2, b2, w3, b3, out);
}

// Round 3
// 345.800 us; speedup vs baseline: 1.1258x; 1.1258x over previous
//
#include <hip/hip_runtime.h>
#include <math.h>

#define NN   8192
#define EE   262144
#define CIN  64
#define DD   192      // IN_C*K = OUT_C*K
#define GG   64
#define NCLS 10
#define D3   576      // 3*DD
#define F1   384
#define F2   192
#define EPSB 1e-5f

// ---------------- setup kernels ----------------

__global__ void count_kernel(const int* __restrict__ ei,
                             const int* __restrict__ batch,
                             int* __restrict__ deg, int* __restrict__ gcnt) {
    int t = blockIdx.x * blockDim.x + threadIdx.x;
    if (t < EE) atomicAdd(&deg[ei[t]], 1);          // row = ei[0:E]
    if (t < NN) atomicAdd(&gcnt[batch[t]], 1);
}

// one block, 256 threads: exclusive scan of deg[8192] -> rowptr, dinv, gstart
__global__ void scan_kernel(const int* __restrict__ deg, int* __restrict__ rowptr,
                            float* __restrict__ dinv, const int* __restrict__ gcnt,
                            int* __restrict__ gstart) {
    __shared__ int part[256];
    int t = threadIdx.x;
    int local[32];
    int base = t * 32;
    int s = 0;
    for (int i = 0; i < 32; i++) { local[i] = s; s += deg[base + i]; }
    part[t] = s;
    __syncthreads();
    for (int off = 1; off < 256; off <<= 1) {
        int v = (t >= off) ? part[t - off] : 0;
        __syncthreads();
        part[t] += v;
        __syncthreads();
    }
    int prefix = (t > 0) ? part[t - 1] : 0;
    for (int i = 0; i < 32; i++) rowptr[base + i] = prefix + local[i];
    if (t == 255) rowptr[NN] = part[255];
    for (int i = 0; i < 32; i++) {
        int d = deg[base + i];
        dinv[base + i] = (d > 0) ? rsqrtf((float)d) : 0.f;
    }
    if (t == 0) {
        int s2 = 0;
        for (int g = 0; g < GG; g++) { gstart[g] = s2; s2 += gcnt[g]; }
    }
}

__global__ void scatter_kernel(const int* __restrict__ ei,
                               const int* __restrict__ rowptr, int* __restrict__ cursor,
                               int* __restrict__ csr_col) {
    int e = blockIdx.x * blockDim.x + threadIdx.x;
    if (e >= EE) return;
    int r = ei[e];
    int c = ei[EE + e];
    int pos = rowptr[r] + atomicAdd(&cursor[r], 1);
    csr_col[pos] = c;
}

// 16 lanes per row (float4 channels), 4 rows per wave.
// out = h_row - dinv[row] * sum_e dinv[col_e] * h[col_e]
__global__ __launch_bounds__(256) void spmm_kernel(const float* __restrict__ hin,
    int in_stride, int in_off,
    const int* __restrict__ rowptr, const int* __restrict__ col,
    const float* __restrict__ dinv,
    float* __restrict__ Hcat, int coff, int write_self) {
    int idx = blockIdx.x * 256 + threadIdx.x;   // N*16 threads
    int row = idx >> 4;
    int q4  = (idx & 15) * 4;
    int s = rowptr[row], e = rowptr[row + 1];
    float ax = 0.f, ay = 0.f, az = 0.f, aw = 0.f;
    for (int p = s; p < e; p++) {
        int c = col[p];
        float dv = dinv[c];
        const float4 h = *(const float4*)&hin[c * in_stride + in_off + q4];
        ax += dv * h.x; ay += dv * h.y; az += dv * h.z; aw += dv * h.w;
    }
    const float4 self = *(const float4*)&hin[row * in_stride + in_off + q4];
    float dr = dinv[row];
    float4 o;
    o.x = self.x - dr * ax; o.y = self.y - dr * ay;
    o.z = self.z - dr * az; o.w = self.w - dr * aw;
    *(float4*)&Hcat[row * DD + coff + q4] = o;
    if (write_self) *(float4*)&Hcat[row * DD + q4] = self;
}

// ------- spectral norm + masked weight, packed k-major float4 layout --------
// Wp4[(k>>2)*DD + t] = { WT[k][t], WT[k+1][t], WT[k+2][t], WT[k+3][t] }

__global__ void specnorm_kernel(const float* __restrict__ W, const float* __restrict__ u,
                                float* __restrict__ Wp) {
    __shared__ float v[DD];
    __shared__ float red[256];
    __shared__ float s_norm, s_sigma;
    int t = threadIdx.x;
    float vv = 0.f;
    if (t < DD) {
        float s = 0.f;
        for (int i = 0; i < DD; i++) s += W[i * DD + t] * u[i];
        v[t] = s;
        vv = s * s;
    }
    red[t] = vv;
    __syncthreads();
    for (int off = 128; off > 0; off >>= 1) {
        if (t < off) red[t] += red[t + off];
        __syncthreads();
    }
    if (t == 0) s_norm = sqrtf(red[0]) + 1e-12f;
    __syncthreads();
    float wv = 0.f;
    if (t < DD) {
        float s = 0.f;
        for (int j = 0; j < DD; j++) s += W[t * DD + j] * v[j];
        wv = u[t] * s;
    }
    red[t] = wv;
    __syncthreads();
    for (int off = 128; off > 0; off >>= 1) {
        if (t < off) red[t] += red[t + off];
        __syncthreads();
    }
    if (t == 0) s_sigma = red[0] / s_norm;
    __syncthreads();
    float inv_sigma = 1.f / s_sigma;
    for (int idx = t; idx < DD * DD; idx += 256) {
        int r = idx / DD, c = idx - r * DD;          // W element (out r, in c)
        float m = (c < CIN * ((r >> 6) + 1)) ? 1.f : 0.f;
        Wp[((c >> 2) * DD + r) * 4 + (c & 3)] = m * W[idx] * inv_sigma;
    }
}

// ------ H = Hcat @ W^T + b, IN PLACE, 8 rows x 192 cols per block -----------
// fused BN1 partial stats (sum, sumsq per channel)

__global__ __launch_bounds__(192) void gemm_kernel(float* __restrict__ Hcat,
    const float* __restrict__ Wp, const float* __restrict__ bias,
    float* __restrict__ bsum, float* __restrict__ bsumsq) {
    __shared__ float hs[8 * DD];
    int t = threadIdx.x;          // t = output channel
    int n0 = blockIdx.x * 8;
    const float4* src = (const float4*)&Hcat[n0 * DD];   // 384 float4s
    float4* dst = (float4*)hs;
    dst[t] = src[t];
    dst[t + 192] = src[t + 192];
    __syncthreads();
    float acc[8];
    float bv = bias[t];
#pragma unroll
    for (int r = 0; r < 8; r++) acc[r] = bv;
    const float4* Wp4 = (const float4*)Wp;
    for (int k4 = 0; k4 < DD / 4; k4++) {
        float4 w = Wp4[k4 * DD + t];
#pragma unroll
        for (int r = 0; r < 8; r++) {
            const float4 h = *(const float4*)&hs[r * DD + k4 * 4];
            acc[r] += h.x * w.x + h.y * w.y + h.z * w.z + h.w * w.w;
        }
    }
    float s = 0.f, ss = 0.f;
#pragma unroll
    for (int r = 0; r < 8; r++) {
        float v = acc[r];
        s += v; ss += v * v;
        Hcat[(n0 + r) * DD + t] = v;
    }
    atomicAdd(&bsum[t], s);
    atomicAdd(&bsumsq[t], ss);
}

// ------ BN1 finalize (inline) + apply + triple pooling ----------------------

__global__ __launch_bounds__(192) void pool_kernel(const float* __restrict__ H,
    const int* __restrict__ gstart, const int* __restrict__ gcnt,
    const float* __restrict__ bsum, const float* __restrict__ bsumsq,
    const float* __restrict__ gamma, const float* __restrict__ beta,
    float* __restrict__ Hg) {
    int g = blockIdx.x, c = threadIdx.x;
    float m = bsum[c] * (1.f / (float)NN);
    float var = bsumsq[c] * (1.f / (float)NN) - m * m;
    float sc = gamma[c] * rsqrtf(var + EPSB);
    float bb = beta[c];
    int s = gstart[g], n = gcnt[g];
    float sum = 0.f, mx = -INFINITY;
    for (int i = 0; i < n; i++) {
        float x = H[(s + i) * DD + c];
        x = sc * (x - m) + bb;
        sum += x;
        mx = fmaxf(mx, x);
    }
    float cf = (float)n;
    Hg[g * D3 + c]          = sum / fmaxf(cf, 1.f);
    Hg[g * D3 + DD + c]     = sum;
    Hg[g * D3 + 2 * DD + c] = mx;
}

// ---------------- BN2 (64 samples x 576 ch), one block ----------------------

__global__ __launch_bounds__(D3) void bn2_kernel(const float* __restrict__ Hg,
    const float* __restrict__ gamma, const float* __restrict__ beta,
    float* __restrict__ Hgn) {
    int c = threadIdx.x;
    float s = 0.f, ss = 0.f;
    for (int g = 0; g < GG; g++) { float x = Hg[g * D3 + c]; s += x; ss += x * x; }
    float m = s / (float)GG;
    float var = ss / (float)GG - m * m;
    float sc = gamma[c] * rsqrtf(var + EPSB);
    float bb = beta[c];
    for (int g = 0; g < GG; g++) Hgn[g * D3 + c] = sc * (Hg[g * D3 + c] - m) + bb;
}

// ---------------- funnel head + log_softmax, one block per graph ------------

__global__ __launch_bounds__(F1) void funnel_kernel(const float* __restrict__ Hgn,
    const float* __restrict__ w1, const float* __restrict__ b1,
    const float* __restrict__ w2, const float* __restrict__ b2,
    const float* __restrict__ w3, const float* __restrict__ b3,
    float* __restrict__ out) {
    __shared__ float hg[D3];
    __shared__ float x1[F1];
    __shared__ float x2[F2];
    __shared__ float lg[NCLS];
    __shared__ float s_lse;
    int g = blockIdx.x, t = threadIdx.x;
    for (int i = t; i < D3; i += F1) hg[i] = Hgn[g * D3 + i];
    __syncthreads();
    {
        const float4* wr = (const float4*)&w1[t * D3];
        const float4* h4 = (const float4*)hg;
        float a = b1[t];
        for (int k = 0; k < D3 / 4; k++) {
            float4 w = wr[k], h = h4[k];
            a += w.x * h.x + w.y * h.y + w.z * h.z + w.w * h.w;
        }
        x1[t] = fmaxf(a, 0.f);
    }
    __syncthreads();
    if (t < F2) {
        const float4* wr = (const float4*)&w2[t * F1];
        const float4* h4 = (const float4*)x1;
        float a = b2[t];
        for (int k = 0; k < F1 / 4; k++) {
            float4 w = wr[k], h = h4[k];
            a += w.x * h.x + w.y * h.y + w.z * h.z + w.w * h.w;
        }
        x2[t] = fmaxf(a, 0.f);
    }
    __syncthreads();
    if (t < NCLS) {
        const float4* wr = (const float4*)&w3[t * F2];
        const float4* h4 = (const float4*)x2;
        float a = b3[t];
        for (int k = 0; k < F2 / 4; k++) {
            float4 w = wr[k], h = h4[k];
            a += w.x * h.x + w.y * h.y + w.z * h.z + w.w * h.w;
        }
        lg[t] = a;
    }
    __syncthreads();
    if (t == 0) {
        float m = lg[0];
        for (int i = 1; i < NCLS; i++) m = fmaxf(m, lg[i]);
        float se = 0.f;
        for (int i = 0; i < NCLS; i++) se += expf(lg[i] - m);
        s_lse = m + logf(se);
    }
    __syncthreads();
    if (t < NCLS) out[g * NCLS + t] = lg[t] - s_lse;
}

// ---------------- launcher ----------------

extern "C" void kernel_launch(void* const* d_in, const int* in_sizes, int n_in,
                              void* d_out, int out_size, void* d_ws, size_t ws_size,
                              hipStream_t stream) {
    (void)in_sizes; (void)n_in; (void)out_size; (void)ws_size;
    const float* x     = (const float*)d_in[0];
    const int*   ei    = (const int*)d_in[1];    // int32 on device (harness contract)
    const int*   batch = (const int*)d_in[2];
    const float* W     = (const float*)d_in[3];
    const float* b     = (const float*)d_in[4];
    const float* u     = (const float*)d_in[5];
    const float* g1    = (const float*)d_in[6];
    const float* be1   = (const float*)d_in[7];
    const float* g2    = (const float*)d_in[8];
    const float* be2   = (const float*)d_in[9];
    const float* w1    = (const float*)d_in[10];
    const float* b1    = (const float*)d_in[11];
    const float* w2    = (const float*)d_in[12];
    const float* b2    = (const float*)d_in[13];
    const float* w3    = (const float*)d_in[14];
    const float* b3    = (const float*)d_in[15];
    float* out = (float*)d_out;
    char*  ws  = (char*)d_ws;

    // ---- workspace layout (bytes), total ~7.6 MB ----
    int*   deg     = (int*)(ws + 0);           // 32768   (zeroed)
    int*   cursor  = (int*)(ws + 32768);       // 32768   (zeroed)
    int*   gcnt    = (int*)(ws + 65536);       // 256     (zeroed)
    float* bsum    = (float*)(ws + 65792);     // 768     (zeroed)
    float* bsumsq  = (float*)(ws + 66560);     // 768     (zeroed; zero region = 67328 B)
    int*   rowptr  = (int*)(ws + 67328);       // 33024
    int*   gstart  = (int*)(ws + 100352);      // 256
    float* dinv    = (float*)(ws + 100608);    // 32768
    int*   csr_col = (int*)(ws + 133376);      // 1048576
    float* Hcat    = (float*)(ws + 1181952);   // 6291456 (also GEMM output, in place)
    float* Wp      = (float*)(ws + 7473408);   // 147456 (packed W^T, k-major float4)
    float* Hg      = (float*)(ws + 7622912);   // 147456
    float* Hgn     = (float*)(ws + 7770368);   // 147456  -> end 7917824

    hipMemsetAsync(ws, 0, 67328, stream);
    count_kernel<<<EE / 256, 256, 0, stream>>>(ei, batch, deg, gcnt);
    scan_kernel<<<1, 256, 0, stream>>>(deg, rowptr, dinv, gcnt, gstart);
    scatter_kernel<<<EE / 256, 256, 0, stream>>>(ei, rowptr, cursor, csr_col);
    // pass 1: read x [N,64], write Hcat col-block 1 (+ copy x into col-block 0)
    spmm_kernel<<<NN * 16 / 256, 256, 0, stream>>>(x, CIN, 0, rowptr, csr_col, dinv, Hcat, CIN, 1);
    // pass 2: read Hcat col-block 1 (strided), write Hcat col-block 2
    spmm_kernel<<<NN * 16 / 256, 256, 0, stream>>>(Hcat, DD, CIN, rowptr, csr_col, dinv, Hcat, 2 * CIN, 0);
    specnorm_kernel<<<1, 256, 0, stream>>>(W, u, Wp);
    gemm_kernel<<<NN / 8, 192, 0, stream>>>(Hcat, Wp, b, bsum, bsumsq);
    pool_kernel<<<GG, 192, 0, stream>>>(Hcat, gstart, gcnt, bsum, bsumsq, g1, be1, Hg);
    bn2_kernel<<<1, D3, 0, stream>>>(Hg, g2, be2, Hgn);
    funnel_kernel<<<GG, F1, 0, stream>>>(Hgn, w1, b1, w2, b2, w3, b3, out);
}

// Round 4
// 310.593 us; speedup vs baseline: 1.2534x; 1.1134x over previous
//
#include <hip/hip_runtime.h>
#include <math.h>

#define NN   8192
#define EE   262144
#define CIN  64
#define DD   192      // IN_C*K = OUT_C*K
#define GG   64
#define NCLS 10
#define D3   576      // 3*DD
#define F1   384
#define F2   192
#define EPSB 1e-5f
#define NB   64       // edge-chunk blocks for count/scatter
#define EPB  (EE / NB) // 4096 edges per block

// ---- per-block LDS histogram of edge rows -> pcnt[b][i] (no global atomics)
__global__ __launch_bounds__(256) void count_kernel(const int* __restrict__ ei,
                                                    int* __restrict__ pcnt) {
    __shared__ int hist[NN];
    int b = blockIdx.x, t = threadIdx.x;
    for (int i = t; i < NN; i += 256) hist[i] = 0;
    __syncthreads();
    int e0 = b * EPB;
    for (int i = t; i < EPB; i += 256) atomicAdd(&hist[ei[e0 + i]], 1);
    __syncthreads();
    for (int i = t; i < NN; i += 256) pcnt[b * NN + i] = hist[i];
}

// ---- per-row reduce + exclusive scan over blocks: off[b][i], deg[i], dinv[i]
// off written in place over pcnt (same thread reads then writes each slot).
__global__ __launch_bounds__(256) void offs_kernel(int* __restrict__ pcnt,
                                                   int* __restrict__ deg,
                                                   float* __restrict__ dinv) {
    int i = blockIdx.x * 256 + threadIdx.x;   // grid = NN/256
    int run = 0;
    for (int b = 0; b < NB; b++) {
        int v = pcnt[b * NN + i];
        pcnt[b * NN + i] = run;               // becomes off[b][i]
        run += v;
    }
    deg[i] = run;
    dinv[i] = (run > 0) ? rsqrtf((float)run) : 0.f;
}

// ---- one block: scan deg -> rowptr; segment boundaries of sorted batch -> gstart
__global__ void scan_kernel(const int* __restrict__ deg, int* __restrict__ rowptr,
                            const int* __restrict__ batch, int* __restrict__ gstart) {
    __shared__ int part[256];
    int t = threadIdx.x;
    int local[32];
    int base = t * 32;
    int s = 0;
    for (int i = 0; i < 32; i++) { local[i] = s; s += deg[base + i]; }
    part[t] = s;
    __syncthreads();
    for (int off = 1; off < 256; off <<= 1) {
        int v = (t >= off) ? part[t - off] : 0;
        __syncthreads();
        part[t] += v;
        __syncthreads();
    }
    int prefix = (t > 0) ? part[t - 1] : 0;
    for (int i = 0; i < 32; i++) rowptr[base + i] = prefix + local[i];
    if (t == 255) rowptr[NN] = part[255];
    // gstart[g] = first index with batch >= g ; gstart[GG] = NN
    for (int i = t; i < NN; i += 256) {
        int b0 = batch[i];
        int b1 = (i + 1 < NN) ? batch[i + 1] : GG;
        if (i == 0) { for (int g = 0; g <= b0; g++) gstart[g] = 0; }
        for (int g = b0 + 1; g <= b1; g++) gstart[g] = i + 1;
    }
}

// ---- CSR build: LDS cursors seeded from rowptr + per-block offsets
__global__ __launch_bounds__(256) void scatter_kernel(const int* __restrict__ ei,
                                                      const int* __restrict__ rowptr,
                                                      const int* __restrict__ off,
                                                      int* __restrict__ csr_col) {
    __shared__ int cur[NN];
    int b = blockIdx.x, t = threadIdx.x;
    for (int i = t; i < NN; i += 256) cur[i] = rowptr[i] + off[b * NN + i];
    __syncthreads();
    int e0 = b * EPB;
    for (int i = t; i < EPB; i += 256) {
        int r = ei[e0 + i];
        int c = ei[EE + e0 + i];
        int pos = atomicAdd(&cur[r], 1);       // LDS atomic
        csr_col[pos] = c;
    }
}

// 16 lanes per row (float4 channels), 4 rows per wave.
// out = h_row - dinv[row] * sum_e dinv[col_e] * h[col_e]
__global__ __launch_bounds__(256) void spmm_kernel(const float* __restrict__ hin,
    int in_stride, int in_off,
    const int* __restrict__ rowptr, const int* __restrict__ col,
    const float* __restrict__ dinv,
    float* __restrict__ Hcat, int coff, int write_self) {
    int idx = blockIdx.x * 256 + threadIdx.x;   // N*16 threads
    int row = idx >> 4;
    int q4  = (idx & 15) * 4;
    int s = rowptr[row], e = rowptr[row + 1];
    float ax = 0.f, ay = 0.f, az = 0.f, aw = 0.f;
    for (int p = s; p < e; p++) {
        int c = col[p];
        float dv = dinv[c];
        const float4 h = *(const float4*)&hin[c * in_stride + in_off + q4];
        ax += dv * h.x; ay += dv * h.y; az += dv * h.z; aw += dv * h.w;
    }
    const float4 self = *(const float4*)&hin[row * in_stride + in_off + q4];
    float dr = dinv[row];
    float4 o;
    o.x = self.x - dr * ax; o.y = self.y - dr * ay;
    o.z = self.z - dr * az; o.w = self.w - dr * aw;
    *(float4*)&Hcat[row * DD + coff + q4] = o;
    if (write_self) *(float4*)&Hcat[row * DD + q4] = self;
}

// ------- spectral norm + masked weight, packed k-major float4 layout --------
// Wp4[(k>>2)*DD + t] = { WT[k][t], WT[k+1][t], WT[k+2][t], WT[k+3][t] }
__global__ void specnorm_kernel(const float* __restrict__ W, const float* __restrict__ u,
                                float* __restrict__ Wp) {
    __shared__ float v[DD];
    __shared__ float red[256];
    __shared__ float s_norm, s_sigma;
    int t = threadIdx.x;
    float vv = 0.f;
    if (t < DD) {
        float s = 0.f;
        for (int i = 0; i < DD; i++) s += W[i * DD + t] * u[i];
        v[t] = s;
        vv = s * s;
    }
    red[t] = vv;
    __syncthreads();
    for (int off = 128; off > 0; off >>= 1) {
        if (t < off) red[t] += red[t + off];
        __syncthreads();
    }
    if (t == 0) s_norm = sqrtf(red[0]) + 1e-12f;
    __syncthreads();
    float wv = 0.f;
    if (t < DD) {
        float s = 0.f;
        for (int j = 0; j < DD; j++) s += W[t * DD + j] * v[j];
        wv = u[t] * s;
    }
    red[t] = wv;
    __syncthreads();
    for (int off = 128; off > 0; off >>= 1) {
        if (t < off) red[t] += red[t + off];
        __syncthreads();
    }
    if (t == 0) s_sigma = red[0] / s_norm;
    __syncthreads();
    float inv_sigma = 1.f / s_sigma;
    for (int idx = t; idx < DD * DD; idx += 256) {
        int r = idx / DD, c = idx - r * DD;          // W element (out r, in c)
        float m = (c < CIN * ((r >> 6) + 1)) ? 1.f : 0.f;
        Wp[((c >> 2) * DD + r) * 4 + (c & 3)] = m * W[idx] * inv_sigma;
    }
}

// ------ H = Hcat @ W^T + b, IN PLACE, 8 rows x 192 cols per block -----------
__global__ __launch_bounds__(192) void gemm_kernel(float* __restrict__ Hcat,
    const float* __restrict__ Wp, const float* __restrict__ bias) {
    __shared__ float hs[8 * DD];
    int t = threadIdx.x;          // t = output channel
    int n0 = blockIdx.x * 8;
    const float4* src = (const float4*)&Hcat[n0 * DD];   // 384 float4s
    float4* dst = (float4*)hs;
    dst[t] = src[t];
    dst[t + 192] = src[t + 192];
    __syncthreads();
    float acc[8];
    float bv = bias[t];
#pragma unroll
    for (int r = 0; r < 8; r++) acc[r] = bv;
    const float4* Wp4 = (const float4*)Wp;
    for (int k4 = 0; k4 < DD / 4; k4++) {
        float4 w = Wp4[k4 * DD + t];
#pragma unroll
        for (int r = 0; r < 8; r++) {
            const float4 h = *(const float4*)&hs[r * DD + k4 * 4];
            acc[r] += h.x * w.x + h.y * w.y + h.z * w.z + h.w * w.w;
        }
    }
#pragma unroll
    for (int r = 0; r < 8; r++) Hcat[(n0 + r) * DD + t] = acc[r];
}

// ------ raw per-graph pooling stats (pre-BN): sum, sumsq, min, max ----------
__global__ __launch_bounds__(192) void pool_kernel(const float* __restrict__ H,
    const int* __restrict__ gstart,
    float* __restrict__ Psum, float* __restrict__ Psq,
    float* __restrict__ Pmin, float* __restrict__ Pmax) {
    int g = blockIdx.x, c = threadIdx.x;
    int s = gstart[g], e = gstart[g + 1];
    float sum = 0.f, sq = 0.f, mn = INFINITY, mx = -INFINITY;
    for (int i = s; i < e; i++) {
        float x = H[i * DD + c];
        sum += x; sq += x * x;
        mn = fminf(mn, x); mx = fmaxf(mx, x);
    }
    Psum[g * DD + c] = sum; Psq[g * DD + c] = sq;
    Pmin[g * DD + c] = mn;  Pmax[g * DD + c] = mx;
}

// ------ BN1 finalize + Hg construction + BN2, one block of 576 --------------
// BN1 is affine per channel: sum(norm) = sc*(sum - n*mu) + n*bb ;
// max(norm) = sc>=0 ? sc*(max-mu)+bb : sc*(min-mu)+bb.
__global__ __launch_bounds__(D3) void head_kernel(
    const float* __restrict__ Psum, const float* __restrict__ Psq,
    const float* __restrict__ Pmin, const float* __restrict__ Pmax,
    const int* __restrict__ gstart,
    const float* __restrict__ g1, const float* __restrict__ be1,
    const float* __restrict__ g2, const float* __restrict__ be2,
    float* __restrict__ Hg, float* __restrict__ Hgn) {
    __shared__ float s_mu[DD], s_sc[DD], s_bb[DD];
    int t = threadIdx.x;
    if (t < DD) {
        float S = 0.f, SS = 0.f;
        for (int g = 0; g < GG; g++) { S += Psum[g * DD + t]; SS += Psq[g * DD + t]; }
        float m = S * (1.f / (float)NN);
        float var = SS * (1.f / (float)NN) - m * m;
        s_mu[t] = m;
        s_sc[t] = g1[t] * rsqrtf(var + EPSB);
        s_bb[t] = be1[t];
    }
    __syncthreads();
    int f = t / DD, c = t - f * DD;   // f: 0=avg 1=sum 2=max (wave-uniform)
    float mu = s_mu[c], sc = s_sc[c], bb = s_bb[c];
    float s2 = 0.f, ss2 = 0.f;
    for (int g = 0; g < GG; g++) {
        float nf = (float)(gstart[g + 1] - gstart[g]);
        float v;
        if (f == 2) {
            float raw = (sc >= 0.f) ? Pmax[g * DD + c] : Pmin[g * DD + c];
            v = sc * (raw - mu) + bb;
        } else {
            float hsum = sc * (Psum[g * DD + c] - nf * mu) + nf * bb;
            v = (f == 0) ? hsum / fmaxf(nf, 1.f) : hsum;
        }
        Hg[g * D3 + t] = v;
        s2 += v; ss2 += v * v;
    }
    float m2 = s2 * (1.f / (float)GG);
    float var2 = ss2 * (1.f / (float)GG) - m2 * m2;
    float sc2 = g2[t] * rsqrtf(var2 + EPSB);
    float bb2 = be2[t];
    for (int g = 0; g < GG; g++)
        Hgn[g * D3 + t] = sc2 * (Hg[g * D3 + t] - m2) + bb2;
}

// ---------------- funnel head + log_softmax, one block per graph ------------
__global__ __launch_bounds__(F1) void funnel_kernel(const float* __restrict__ Hgn,
    const float* __restrict__ w1, const float* __restrict__ b1,
    const float* __restrict__ w2, const float* __restrict__ b2,
    const float* __restrict__ w3, const float* __restrict__ b3,
    float* __restrict__ out) {
    __shared__ float hg[D3];
    __shared__ float x1[F1];
    __shared__ float x2[F2];
    __shared__ float lg[NCLS];
    __shared__ float s_lse;
    int g = blockIdx.x, t = threadIdx.x;
    for (int i = t; i < D3; i += F1) hg[i] = Hgn[g * D3 + i];
    __syncthreads();
    {
        const float4* wr = (const float4*)&w1[t * D3];
        const float4* h4 = (const float4*)hg;
        float a = b1[t];
        for (int k = 0; k < D3 / 4; k++) {
            float4 w = wr[k], h = h4[k];
            a += w.x * h.x + w.y * h.y + w.z * h.z + w.w * h.w;
        }
        x1[t] = fmaxf(a, 0.f);
    }
    __syncthreads();
    if (t < F2) {
        const float4* wr = (const float4*)&w2[t * F1];
        const float4* h4 = (const float4*)x1;
        float a = b2[t];
        for (int k = 0; k < F1 / 4; k++) {
            float4 w = wr[k], h = h4[k];
            a += w.x * h.x + w.y * h.y + w.z * h.z + w.w * h.w;
        }
        x2[t] = fmaxf(a, 0.f);
    }
    __syncthreads();
    if (t < NCLS) {
        const float4* wr = (const float4*)&w3[t * F2];
        const float4* h4 = (const float4*)x2;
        float a = b3[t];
        for (int k = 0; k < F2 / 4; k++) {
            float4 w = wr[k], h = h4[k];
            a += w.x * h.x + w.y * h.y + w.z * h.z + w.w * h.w;
        }
        lg[t] = a;
    }
    __syncthreads();
    if (t == 0) {
        float m = lg[0];
        for (int i = 1; i < NCLS; i++) m = fmaxf(m, lg[i]);
        float se = 0.f;
        for (int i = 0; i < NCLS; i++) se += expf(lg[i] - m);
        s_lse = m + logf(se);
    }
    __syncthreads();
    if (t < NCLS) out[g * NCLS + t] = lg[t] - s_lse;
}

// ---------------- launcher ----------------

extern "C" void kernel_launch(void* const* d_in, const int* in_sizes, int n_in,
                              void* d_out, int out_size, void* d_ws, size_t ws_size,
                              hipStream_t stream) {
    (void)in_sizes; (void)n_in; (void)out_size; (void)ws_size;
    const float* x     = (const float*)d_in[0];
    const int*   ei    = (const int*)d_in[1];    // int32 on device (harness contract)
    const int*   batch = (const int*)d_in[2];
    const float* W     = (const float*)d_in[3];
    const float* b     = (const float*)d_in[4];
    const float* u     = (const float*)d_in[5];
    const float* g1    = (const float*)d_in[6];
    const float* be1   = (const float*)d_in[7];
    const float* g2    = (const float*)d_in[8];
    const float* be2   = (const float*)d_in[9];
    const float* w1    = (const float*)d_in[10];
    const float* b1    = (const float*)d_in[11];
    const float* w2    = (const float*)d_in[12];
    const float* b2    = (const float*)d_in[13];
    const float* w3    = (const float*)d_in[14];
    const float* b3    = (const float*)d_in[15];
    float* out = (float*)d_out;
    char*  ws  = (char*)d_ws;

    // ---- workspace layout (bytes), ~7.7 MB total ----
    int*   rowptr  = (int*)(ws + 0);           //   33024
    int*   gstart  = (int*)(ws + 33024);       //     512 (65 ints)
    int*   deg     = (int*)(ws + 33536);       //   32768
    float* dinv    = (float*)(ws + 66304);     //   32768
    float* Wp      = (float*)(ws + 99072);     //  147456
    float* Psum    = (float*)(ws + 246528);    //   49152
    float* Psq     = (float*)(ws + 295680);    //   49152
    float* Pmin    = (float*)(ws + 344832);    //   49152
    float* Pmax    = (float*)(ws + 393984);    //   49152
    float* Hg      = (float*)(ws + 443136);    //  147456
    float* Hgn     = (float*)(ws + 590592);    //  147456
    int*   csr_col = (int*)(ws + 738048);      // 1048576
    float* Hcat    = (float*)(ws + 1786624);   // 6291456 -> end 8078080
    int*   pcnt    = (int*)(ws + 1786624);     // 2 MB, ALIASES Hcat (dead before spmm)

    count_kernel<<<NB, 256, 0, stream>>>(ei, pcnt);
    offs_kernel<<<NN / 256, 256, 0, stream>>>(pcnt, deg, dinv);
    scan_kernel<<<1, 256, 0, stream>>>(deg, rowptr, batch, gstart);
    scatter_kernel<<<NB, 256, 0, stream>>>(ei, rowptr, pcnt, csr_col);
    // pass 1: read x [N,64], write Hcat col-block 1 (+ copy x into col-block 0)
    spmm_kernel<<<NN * 16 / 256, 256, 0, stream>>>(x, CIN, 0, rowptr, csr_col, dinv, Hcat, CIN, 1);
    // pass 2: read Hcat col-block 1 (strided), write Hcat col-block 2
    spmm_kernel<<<NN * 16 / 256, 256, 0, stream>>>(Hcat, DD, CIN, rowptr, csr_col, dinv, Hcat, 2 * CIN, 0);
    specnorm_kernel<<<1, 256, 0, stream>>>(W, u, Wp);
    gemm_kernel<<<NN / 8, 192, 0, stream>>>(Hcat, Wp, b);
    pool_kernel<<<GG, 192, 0, stream>>>(Hcat, gstart, Psum, Psq, Pmin, Pmax);
    head_kernel<<<1, D3, 0, stream>>>(Psum, Psq, Pmin, Pmax, gstart, g1, be1, g2, be2, Hg, Hgn);
    funnel_kernel<<<GG, F1, 0, stream>>>(Hgn, w1, b1, w2, b2, w3, b3, out);
}